// Round 5
// baseline (4473.056 us; speedup 1.0000x reference)
//
#include <hip/hip_runtime.h>
#include <hip/hip_bf16.h>

// SPINN: word GEMM + persistent level-scheduled TreeLSTM with software grid barrier.
// B=128, L=64, E=512, H=512, T=127.

#define Bn 128
#define Ln 64
#define En 512
#define Hn 512
#define Tn 127
#define LEAF_ROWS (Bn*Ln)        // 8192 word rows
#define NODE_ROWS (Bn*(Ln-1))    // 8064 reduce-node rows
#define TOT_ROWS (LEAF_ROWS+NODE_ROWS)
#define CAPL 4096                // max rows in any level (level 1: 128*32)
#define NLVL 64
#define GATE_STRIDE (512*1024)   // WT element stride between gates
#define NBLK 512                 // persistent grid (2 blocks/CU capacity guaranteed)

typedef __attribute__((ext_vector_type(8))) short bf16x8;
typedef __attribute__((ext_vector_type(4))) float f32x4;

static __device__ __forceinline__ float bf2f(unsigned short u){
  unsigned v = ((unsigned)u) << 16;
  float f; __builtin_memcpy(&f, &v, 4); return f;
}
static __device__ __forceinline__ unsigned short f2bf(float f){
  unsigned u; __builtin_memcpy(&u, &f, 4);
  u = u + 0x7FFFu + ((u >> 16) & 1u);   // round-nearest-even
  return (unsigned short)(u >> 16);
}
static __device__ __forceinline__ float sigm(float x){
  return 1.0f / (1.0f + __expf(-x));
}
static __device__ __forceinline__ float tanh_fast(float x){
  x = fminf(fmaxf(x, -15.0f), 15.0f);
  float t = __expf(2.0f * x);
  return (t - 1.0f) / (t + 1.0f);
}

// Device-scope generation barrier. bar[0]=arrive counter, bar[1]=generation.
// Release: __threadfence (agent fence -> L2 writeback on gfx950) before arrive.
// Acquire: spin with acquire loads, then __threadfence (L1/L2 inv) after wake.
static __device__ __forceinline__ void grid_barrier(int* bar, int nb){
  __syncthreads();
  if (threadIdx.x == 0){
    __threadfence();
    int g = __hip_atomic_load(&bar[1], __ATOMIC_RELAXED, __HIP_MEMORY_SCOPE_AGENT);
    int prev = __hip_atomic_fetch_add(&bar[0], 1, __ATOMIC_ACQ_REL, __HIP_MEMORY_SCOPE_AGENT);
    if (prev == nb - 1){
      __hip_atomic_store(&bar[0], 0, __ATOMIC_RELAXED, __HIP_MEMORY_SCOPE_AGENT);
      __hip_atomic_store(&bar[1], g + 1, __ATOMIC_RELEASE, __HIP_MEMORY_SCOPE_AGENT);
    } else {
      while (__hip_atomic_load(&bar[1], __ATOMIC_ACQUIRE, __HIP_MEMORY_SCOPE_AGENT) == g)
        __builtin_amdgcn_s_sleep(2);
    }
    __threadfence();
  }
  __syncthreads();
}

// ---------------- convert / transpose helpers ----------------

__global__ void cvt_vec4(const float4* __restrict__ x, ushort4* __restrict__ y, int n4){
  int i = blockIdx.x * 256 + threadIdx.x;
  if (i < n4){
    float4 v = x[i];
    ushort4 o;
    o.x = f2bf(v.x); o.y = f2bf(v.y); o.z = f2bf(v.z); o.w = f2bf(v.w);
    y[i] = o;
  }
}

// dstT[c*DS + koff + r] = bf16(src[r*CS + c]); tiles 32x32, block (32,8)
__global__ void transpose_cvt(const float* __restrict__ src, unsigned short* __restrict__ dstT,
                              int CS, int DS, int koff){
  __shared__ float tile[32][33];
  int c0 = blockIdx.x * 32, r0 = blockIdx.y * 32;
  int tx = threadIdx.x, ty = threadIdx.y;
  for (int i = ty; i < 32; i += 8) tile[i][tx] = src[(size_t)(r0 + i) * CS + c0 + tx];
  __syncthreads();
  for (int i = ty; i < 32; i += 8)
    dstT[(size_t)(c0 + i) * DS + koff + r0 + tx] = f2bf(tile[tx][i]);
}

// ---------------- control precompute: stack sim -> per-LEVEL dataflow ----------------
// One block, 128 threads. Also zeroes the grid-barrier state each call.
__global__ void precompute_ctrl(const int* __restrict__ trans,
                                int* __restrict__ srcL, int* __restrict__ srcR,
                                int* __restrict__ dstv, int* __restrict__ cnt,
                                int* __restrict__ outsrc, int* __restrict__ bar){
  __shared__ int stk[Bn][Ln + 1];  // padded
  __shared__ int scnt[NLVL];
  __shared__ int smax;
  int b = threadIdx.x;
  if (b < NLVL) scnt[b] = 0;
  if (b == 0){ smax = 0; bar[0] = 0; bar[1] = 0; }
  __syncthreads();
  int sp = 0, bp = 0, nodecnt = 0;
  int act_next = trans[b * Tn];
  for (int t = 0; t < Tn; t++){
    int act = act_next;
    if (t + 1 < Tn) act_next = trans[b * Tn + t + 1];
    int ops = Tn - t;
    if (sp > ops) act = 2;                       // forced REDUCE (matches ref)
    if (act == 2){                               // REDUCE
      int R = stk[b][sp - 1], L = stk[b][sp - 2];
      int lvl = max(R >> 20, L >> 20) + 1;       // 1..63
      int slot = atomicAdd(&scnt[lvl], 1);
      srcL[lvl * CAPL + slot] = (L & 0xFFFFF) * Hn;
      srcR[lvl * CAPL + slot] = (R & 0xFFFFF) * Hn;
      int noderow = LEAF_ROWS + b * (Ln - 1) + nodecnt;
      dstv[lvl * CAPL + slot] = noderow * Hn;
      stk[b][sp - 2] = noderow | (lvl << 20);
      sp -= 1; nodecnt++;
    } else {                                     // SHIFT (leaf: level 0)
      stk[b][sp] = b * Ln + min(bp, Ln - 1);
      sp += 1; bp += 1;
    }
  }
  int root = stk[b][max(sp - 1, 0)];
  outsrc[b] = (root & 0xFFFFF) * Hn;
  atomicMax(&smax, root >> 20);
  __syncthreads();
  if (b < NLVL) cnt[b] = scnt[b];
  __syncthreads();
  if (b == 0) cnt[0] = smax;                     // level 0 slot repurposed: maxlvl
}

// ---------------- word GEMM: out = sentence @ W_word + b_word ----------------
// M=8192, K=512, N=1024. Block tile 64M x 128N, 4 waves as 2x2.
// grid x = N-tile (8) -> XCD-affine: B slice L2-resident per XCD.
__global__ __launch_bounds__(256) void word_gemm(
    const unsigned short* __restrict__ SB, const unsigned short* __restrict__ WwT,
    const float* __restrict__ b_word,
    unsigned short* __restrict__ HB, float* __restrict__ CF){
  int nt = blockIdx.x;            // 8 N-tiles (XCD-affine)
  int mt = blockIdx.y;            // 128 M-tiles
  int tid = threadIdx.x, w = tid >> 6, lane = tid & 63;
  int wm = w >> 1, wn = w & 1;
  int rc = lane & 15, lg = lane >> 4;
  const unsigned short* ap0 = SB + (size_t)(mt * 64 + wm * 32 + rc) * En + lg * 8;
  const unsigned short* ap1 = ap0 + (size_t)16 * En;
  const unsigned short* bp0 = WwT + (size_t)(nt * 128 + wn * 64 + rc) * En + lg * 8;
  f32x4 acc[2][4];
  #pragma unroll
  for (int h = 0; h < 2; h++)
    #pragma unroll
    for (int nb = 0; nb < 4; nb++) acc[h][nb] = (f32x4){0.f,0.f,0.f,0.f};
  #pragma unroll 4
  for (int k0 = 0; k0 < En; k0 += 32){
    bf16x8 a0 = *(const bf16x8*)(ap0 + k0);
    bf16x8 a1 = *(const bf16x8*)(ap1 + k0);
    #pragma unroll
    for (int nb = 0; nb < 4; nb++){
      bf16x8 bb = *(const bf16x8*)(bp0 + (size_t)nb * 16 * En + k0);
      acc[0][nb] = __builtin_amdgcn_mfma_f32_16x16x32_bf16(a0, bb, acc[0][nb], 0, 0, 0);
      acc[1][nb] = __builtin_amdgcn_mfma_f32_16x16x32_bf16(a1, bb, acc[1][nb], 0, 0, 0);
    }
  }
  #pragma unroll
  for (int nb = 0; nb < 4; nb++){
    int col = nt * 128 + wn * 64 + nb * 16 + rc;
    float bw = b_word[col];
    #pragma unroll
    for (int h = 0; h < 2; h++){
      #pragma unroll
      for (int q = 0; q < 4; q++){
        int row = mt * 64 + wm * 32 + h * 16 + lg * 4 + q;
        float v = acc[h][nb][q] + bw;
        if (col < Hn) HB[(size_t)row * Hn + col] = f2bf(v);
        else          CF[(size_t)row * Hn + (col - Hn)] = v;
      }
    }
  }
}

// ---------------- persistent tree kernel (software grid barrier) ----------------
// 512 blocks = 32 u-blocks x 16 m-groups, 256 threads (4 waves), 2 blocks/CU.
// Per level: tasks = 16-row x 16-u tiles; K=1024 split over 4 waves (256 each),
// partials combined in LDS, fused TreeLSTM epilogue; grid barrier between levels.
// u-block ub -> XCD ub%8: per-XCD weight slice 640KB stays L2-resident.
__global__ __launch_bounds__(256, 2) void tree_kernel(
    unsigned short* __restrict__ HB, float* __restrict__ CF,
    const unsigned short* __restrict__ WT, const float* __restrict__ b_red,
    const int* __restrict__ srcL, const int* __restrict__ srcR,
    const int* __restrict__ dstv, const int* __restrict__ cnt,
    const int* __restrict__ outsrc, float* __restrict__ out, int* bar){
  __shared__ float part[4][5][16][20];   // [wave][gate][row][col(+pad)]
  int bid = blockIdx.x;
  int ub = bid & 31, mg = bid >> 5;      // u-block 0..31, m-group 0..15
  int tid = threadIdx.x, w = tid >> 6, lane = tid & 63;
  int rc = lane & 15, lg = lane >> 4;
  int u0 = ub * 16;
  int eu = tid & 15, er = tid >> 4;      // epilogue coords (er 0..15, eu 0..15)
  int colu = u0 + eu;
  float bg  = b_red[colu];
  float bi  = b_red[Hn + colu];
  float bf1 = b_red[2 * Hn + colu];
  float bf2 = b_red[3 * Hn + colu];
  float bo  = b_red[4 * Hn + colu];
  int khalf = w >> 1, kq = w & 1;        // wave -> K quarter
  const unsigned short* bbase = WT + (size_t)(u0 + rc) * 1024 + khalf * 512 + kq * 256 + lg * 8;
  int maxlvl = cnt[0];

  for (int lvl = 1; lvl <= maxlvl; ++lvl){
    int nr = cnt[lvl];
    const int* sL = srcL + lvl * CAPL;
    const int* sR = srcR + lvl * CAPL;
    const int* dl = dstv + lvl * CAPL;
    int ntl = (nr + 15) >> 4;
    for (int tile = mg; tile < ntl; tile += 16){
      int irow = min(tile * 16 + rc, nr - 1);
      int offA = (khalf ? sR : sL)[irow];
      const unsigned short* ap = HB + offA + kq * 256 + lg * 8;
      f32x4 a0v = {0.f,0.f,0.f,0.f}, a1v = a0v, a2v = a0v, a3v = a0v, a4v = a0v;
      #pragma unroll
      for (int j = 0; j < 8; ++j){
        bf16x8 a  = *(const bf16x8*)(ap + j * 32);
        bf16x8 b0 = *(const bf16x8*)(bbase + j * 32);
        bf16x8 b1 = *(const bf16x8*)(bbase + GATE_STRIDE + j * 32);
        bf16x8 b2 = *(const bf16x8*)(bbase + 2 * GATE_STRIDE + j * 32);
        bf16x8 b3 = *(const bf16x8*)(bbase + 3 * GATE_STRIDE + j * 32);
        bf16x8 b4 = *(const bf16x8*)(bbase + 4 * GATE_STRIDE + j * 32);
        a0v = __builtin_amdgcn_mfma_f32_16x16x32_bf16(a, b0, a0v, 0, 0, 0);
        a1v = __builtin_amdgcn_mfma_f32_16x16x32_bf16(a, b1, a1v, 0, 0, 0);
        a2v = __builtin_amdgcn_mfma_f32_16x16x32_bf16(a, b2, a2v, 0, 0, 0);
        a3v = __builtin_amdgcn_mfma_f32_16x16x32_bf16(a, b3, a3v, 0, 0, 0);
        a4v = __builtin_amdgcn_mfma_f32_16x16x32_bf16(a, b4, a4v, 0, 0, 0);
      }
      #pragma unroll
      for (int q = 0; q < 4; ++q){
        int r = lg * 4 + q;                      // C/D: row=(lane>>4)*4+q, col=lane&15
        part[w][0][r][rc] = a0v[q];
        part[w][1][r][rc] = a1v[q];
        part[w][2][r][rc] = a2v[q];
        part[w][3][r][rc] = a3v[q];
        part[w][4][r][rc] = a4v[q];
      }
      __syncthreads();
      int i = tile * 16 + er;
      if (i < nr){
        float s0 = part[0][0][er][eu] + part[1][0][er][eu] + part[2][0][er][eu] + part[3][0][er][eu];
        float s1 = part[0][1][er][eu] + part[1][1][er][eu] + part[2][1][er][eu] + part[3][1][er][eu];
        float s2 = part[0][2][er][eu] + part[1][2][er][eu] + part[2][2][er][eu] + part[3][2][er][eu];
        float s3 = part[0][3][er][eu] + part[1][3][er][eu] + part[2][3][er][eu] + part[3][3][er][eu];
        float s4 = part[0][4][er][eu] + part[1][4][er][eu] + part[2][4][er][eu] + part[3][4][er][eu];
        float gv  = tanh_fast(s0 + bg);
        float iv  = sigm(s1 + bi);
        float f1v = sigm(s2 + bf1);
        float f2v = sigm(s3 + bf2);
        float ov  = sigm(s4 + bo);
        int oL = sL[i], oR = sR[i], oD = dl[i];
        float cl = CF[oL + colu], cr = CF[oR + colu];
        float cv = gv * iv + f1v * cl + f2v * cr;
        float hv = ov * tanh_fast(cv);
        CF[oD + colu] = cv;
        HB[oD + colu] = f2bf(hv);
      }
      __syncthreads();
    }
    grid_barrier(bar, NBLK);
  }

  // final gather: out[b][u] = f32(h_root[b][u])
  if (bid < Bn){
    int src = outsrc[bid];
    out[bid * Hn + tid]       = bf2f(HB[src + tid]);
    out[bid * Hn + tid + 256] = bf2f(HB[src + tid + 256]);
  }
}

// ---------------- launch ----------------
extern "C" void kernel_launch(void* const* d_in, const int* in_sizes, int n_in,
                              void* d_out, int out_size, void* d_ws, size_t ws_size,
                              hipStream_t stream){
  (void)in_sizes; (void)n_in; (void)out_size; (void)ws_size;
  const float* sentence = (const float*)d_in[0];
  const int*   trans    = (const int*)d_in[1];
  const float* W_word   = (const float*)d_in[2];
  const float* b_word   = (const float*)d_in[3];
  const float* W_left   = (const float*)d_in[4];
  const float* W_right  = (const float*)d_in[5];
  const float* b_red    = (const float*)d_in[6];

  char* ws = (char*)d_ws;
  size_t off = 0;
  auto alloc = [&](size_t bytes) -> void* {
    void* p = ws + off;
    off += (bytes + 255) & ~((size_t)255);
    return p;
  };
  unsigned short* HB  = (unsigned short*)alloc((size_t)TOT_ROWS * Hn * 2); // bf16 h
  float*          CF  = (float*)alloc((size_t)TOT_ROWS * Hn * 4);          // f32 c
  unsigned short* WT  = (unsigned short*)alloc((size_t)2560 * 1024 * 2);   // [W_left;W_right]^T bf16
  unsigned short* SB  = (unsigned short*)alloc((size_t)LEAF_ROWS * En * 2);// sentence bf16
  unsigned short* WwT = (unsigned short*)alloc((size_t)1024 * En * 2);     // W_word^T bf16
  int* srcL   = (int*)alloc((size_t)NLVL * CAPL * 4);
  int* srcR   = (int*)alloc((size_t)NLVL * CAPL * 4);
  int* dstv   = (int*)alloc((size_t)NLVL * CAPL * 4);
  int* cnt    = (int*)alloc((size_t)NLVL * 4);
  int* outsrc = (int*)alloc((size_t)Bn * 4);
  int* bar    = (int*)alloc((size_t)64 * 4);
  float* outp = (float*)d_out;

  cvt_vec4<<<(LEAF_ROWS * En / 4) / 256, 256, 0, stream>>>((const float4*)sentence, (ushort4*)SB, LEAF_ROWS * En / 4);
  transpose_cvt<<<dim3(1024 / 32, En / 32), dim3(32, 8), 0, stream>>>(W_word, WwT, 1024, En, 0);
  transpose_cvt<<<dim3(2560 / 32, Hn / 32), dim3(32, 8), 0, stream>>>(W_left, WT, 2560, 1024, 0);
  transpose_cvt<<<dim3(2560 / 32, Hn / 32), dim3(32, 8), 0, stream>>>(W_right, WT, 2560, 1024, 512);
  precompute_ctrl<<<1, 128, 0, stream>>>(trans, srcL, srcR, dstv, cnt, outsrc, bar);
  word_gemm<<<dim3(8, LEAF_ROWS / 64), 256, 0, stream>>>(SB, WwT, b_word, HB, CF);
  tree_kernel<<<NBLK, 256, 0, stream>>>(HB, CF, WT, b_red, srcL, srcR, dstv, cnt, outsrc, outp, bar);
}

// Round 6
// 4344.043 us; speedup vs baseline: 1.0297x; 1.0297x over previous
//
#include <hip/hip_runtime.h>
#include <hip/hip_bf16.h>

// SPINN: word GEMM + persistent level-scheduled TreeLSTM, flag-array grid barrier.
// B=128, L=64, E=512, H=512, T=127.

#define Bn 128
#define Ln 64
#define En 512
#define Hn 512
#define Tn 127
#define LEAF_ROWS (Bn*Ln)        // 8192 word rows
#define NODE_ROWS (Bn*(Ln-1))    // 8064 reduce-node rows
#define TOT_ROWS (LEAF_ROWS+NODE_ROWS)
#define CAPL 4096                // max rows in any level (level 1: 128*32)
#define NLVL 64
#define GATE_STRIDE (512*1024)   // WT element stride between gates
#define NBLK 512                 // persistent grid (2 blocks/CU capacity guaranteed)
#define FPAD 16                  // flag padding (one flag per 64B line)

typedef __attribute__((ext_vector_type(8))) short bf16x8;
typedef __attribute__((ext_vector_type(4))) float f32x4;

static __device__ __forceinline__ float bf2f(unsigned short u){
  unsigned v = ((unsigned)u) << 16;
  float f; __builtin_memcpy(&f, &v, 4); return f;
}
static __device__ __forceinline__ unsigned short f2bf(float f){
  unsigned u; __builtin_memcpy(&u, &f, 4);
  u = u + 0x7FFFu + ((u >> 16) & 1u);   // round-nearest-even
  return (unsigned short)(u >> 16);
}
static __device__ __forceinline__ float sigm(float x){
  return 1.0f / (1.0f + __expf(-x));
}
static __device__ __forceinline__ float tanh_fast(float x){
  x = fminf(fmaxf(x, -15.0f), 15.0f);
  float t = __expf(2.0f * x);
  return (t - 1.0f) / (t + 1.0f);
}

// Flag-array grid barrier (epoch-monotonic). flags[i*FPAD] = per-block arrival
// epoch; flags[NBLK*FPAD] = generation. Arrivals are independent release-stores
// (no same-address RMW serialization); block 0 polls, then releases gen.
static __device__ __forceinline__ void grid_barrier(int* flags, int bid, int epoch){
  __syncthreads();
  int* gen = flags + NBLK * FPAD;
  if (bid == 0){
    for (int i = threadIdx.x; i < NBLK; i += 256){
      if (i != 0){
        while (__hip_atomic_load(&flags[i * FPAD], __ATOMIC_RELAXED, __HIP_MEMORY_SCOPE_AGENT) < epoch)
          __builtin_amdgcn_s_sleep(1);
      }
    }
    __syncthreads();
    if (threadIdx.x == 0){
      __threadfence();   // acquire (after observed flags) + release (my writes) at agent scope
      __hip_atomic_store(gen, epoch, __ATOMIC_RELEASE, __HIP_MEMORY_SCOPE_AGENT);
    }
  } else {
    if (threadIdx.x == 0){
      __threadfence();   // make this block's level writes agent-visible
      __hip_atomic_store(&flags[bid * FPAD], epoch, __ATOMIC_RELEASE, __HIP_MEMORY_SCOPE_AGENT);
      while (__hip_atomic_load(gen, __ATOMIC_ACQUIRE, __HIP_MEMORY_SCOPE_AGENT) < epoch)
        __builtin_amdgcn_s_sleep(2);
      __threadfence();   // invalidate caches before reading other blocks' data
    }
  }
  __syncthreads();
}

// ---------------- convert / transpose helpers ----------------

__global__ void cvt_vec4(const float4* __restrict__ x, ushort4* __restrict__ y, int n4){
  int i = blockIdx.x * 256 + threadIdx.x;
  if (i < n4){
    float4 v = x[i];
    ushort4 o;
    o.x = f2bf(v.x); o.y = f2bf(v.y); o.z = f2bf(v.z); o.w = f2bf(v.w);
    y[i] = o;
  }
}

// dstT[c*DS + koff + r] = bf16(src[r*CS + c]); tiles 32x32, block (32,8)
__global__ void transpose_cvt(const float* __restrict__ src, unsigned short* __restrict__ dstT,
                              int CS, int DS, int koff){
  __shared__ float tile[32][33];
  int c0 = blockIdx.x * 32, r0 = blockIdx.y * 32;
  int tx = threadIdx.x, ty = threadIdx.y;
  for (int i = ty; i < 32; i += 8) tile[i][tx] = src[(size_t)(r0 + i) * CS + c0 + tx];
  __syncthreads();
  for (int i = ty; i < 32; i += 8)
    dstT[(size_t)(c0 + i) * DS + koff + r0 + tx] = f2bf(tile[tx][i]);
}

// ---------------- control precompute: stack sim -> per-LEVEL dataflow ----------------
// One block, 128 threads. Also zeroes the barrier flags each call (deterministic
// across graph replays). Node level = 1 + max(level(l), level(r)).
__global__ void precompute_ctrl(const int* __restrict__ trans,
                                int* __restrict__ srcL, int* __restrict__ srcR,
                                int* __restrict__ dstv, int* __restrict__ cnt,
                                int* __restrict__ outsrc, int* __restrict__ bar){
  __shared__ int stk[Bn][Ln + 1];  // padded
  __shared__ int scnt[NLVL];
  __shared__ int smax;
  int b = threadIdx.x;
  if (b < NLVL) scnt[b] = 0;
  if (b == 0) smax = 0;
  for (int i = b; i < NBLK * FPAD + 1; i += 128) bar[i] = 0;
  __syncthreads();
  int sp = 0, bp = 0, nodecnt = 0;
  int act_next = trans[b * Tn];
  for (int t = 0; t < Tn; t++){
    int act = act_next;
    if (t + 1 < Tn) act_next = trans[b * Tn + t + 1];
    int ops = Tn - t;
    if (sp > ops) act = 2;                       // forced REDUCE (matches ref)
    if (act == 2){                               // REDUCE
      int R = stk[b][sp - 1], L = stk[b][sp - 2];
      int lvl = max(R >> 20, L >> 20) + 1;       // 1..63
      int slot = atomicAdd(&scnt[lvl], 1);
      srcL[lvl * CAPL + slot] = (L & 0xFFFFF) * Hn;
      srcR[lvl * CAPL + slot] = (R & 0xFFFFF) * Hn;
      int noderow = LEAF_ROWS + b * (Ln - 1) + nodecnt;
      dstv[lvl * CAPL + slot] = noderow * Hn;
      stk[b][sp - 2] = noderow | (lvl << 20);
      sp -= 1; nodecnt++;
    } else {                                     // SHIFT (leaf: level 0)
      stk[b][sp] = b * Ln + min(bp, Ln - 1);
      sp += 1; bp += 1;
    }
  }
  int root = stk[b][max(sp - 1, 0)];
  outsrc[b] = (root & 0xFFFFF) * Hn;
  atomicMax(&smax, root >> 20);
  __syncthreads();
  if (b < NLVL) cnt[b] = scnt[b];
  __syncthreads();
  if (b == 0) cnt[0] = smax;                     // level 0 slot repurposed: maxlvl
}

// ---------------- word GEMM: out = sentence @ W_word + b_word ----------------
// M=8192, K=512, N=1024. Block tile 64M x 128N, 4 waves as 2x2.
// grid x = N-tile (8) -> XCD-affine: B slice L2-resident per XCD.
__global__ __launch_bounds__(256) void word_gemm(
    const unsigned short* __restrict__ SB, const unsigned short* __restrict__ WwT,
    const float* __restrict__ b_word,
    unsigned short* __restrict__ HB, float* __restrict__ CF){
  int nt = blockIdx.x;            // 8 N-tiles (XCD-affine)
  int mt = blockIdx.y;            // 128 M-tiles
  int tid = threadIdx.x, w = tid >> 6, lane = tid & 63;
  int wm = w >> 1, wn = w & 1;
  int rc = lane & 15, lg = lane >> 4;
  const unsigned short* ap0 = SB + (size_t)(mt * 64 + wm * 32 + rc) * En + lg * 8;
  const unsigned short* ap1 = ap0 + (size_t)16 * En;
  const unsigned short* bp0 = WwT + (size_t)(nt * 128 + wn * 64 + rc) * En + lg * 8;
  f32x4 acc[2][4];
  #pragma unroll
  for (int h = 0; h < 2; h++)
    #pragma unroll
    for (int nb = 0; nb < 4; nb++) acc[h][nb] = (f32x4){0.f,0.f,0.f,0.f};
  #pragma unroll 4
  for (int k0 = 0; k0 < En; k0 += 32){
    bf16x8 a0 = *(const bf16x8*)(ap0 + k0);
    bf16x8 a1 = *(const bf16x8*)(ap1 + k0);
    #pragma unroll
    for (int nb = 0; nb < 4; nb++){
      bf16x8 bb = *(const bf16x8*)(bp0 + (size_t)nb * 16 * En + k0);
      acc[0][nb] = __builtin_amdgcn_mfma_f32_16x16x32_bf16(a0, bb, acc[0][nb], 0, 0, 0);
      acc[1][nb] = __builtin_amdgcn_mfma_f32_16x16x32_bf16(a1, bb, acc[1][nb], 0, 0, 0);
    }
  }
  #pragma unroll
  for (int nb = 0; nb < 4; nb++){
    int col = nt * 128 + wn * 64 + nb * 16 + rc;
    float bw = b_word[col];
    #pragma unroll
    for (int h = 0; h < 2; h++){
      #pragma unroll
      for (int q = 0; q < 4; q++){
        int row = mt * 64 + wm * 32 + h * 16 + lg * 4 + q;
        float v = acc[h][nb][q] + bw;
        if (col < Hn) HB[(size_t)row * Hn + col] = f2bf(v);
        else          CF[(size_t)row * Hn + (col - Hn)] = v;
      }
    }
  }
}

// ---------------- per-level tile processor (templated M-repeat) ----------------
// MR 16-row fragments per task; K=1024 split over 4 waves (256 each); partials
// combined per-16-row-subtile in a fixed 25.6KB LDS buffer; fused LSTM + scatter.
template<int MR>
static __device__ __forceinline__ void do_tiles_level(
    int nr, int mg, const int* sL, const int* sR, const int* dl,
    unsigned short* __restrict__ HB, float* __restrict__ CF,
    const unsigned short* __restrict__ bbase, float (*part)[5][16][20],
    int w, int rc, int lg, int khalf, int kq, int er, int eu, int colu,
    float bg, float bi, float bf1, float bf2, float bo)
{
  const int MB = 16 * MR;
  int ntl = (nr + MB - 1) / MB;
  for (int tile = mg; tile < ntl; tile += 16){
    int base = tile * MB;
    int offA[MR];
    #pragma unroll
    for (int m = 0; m < MR; m++){
      int i = min(base + m * 16 + rc, nr - 1);
      offA[m] = (khalf ? sR : sL)[i];
    }
    f32x4 acc[5][MR];
    #pragma unroll
    for (int g = 0; g < 5; g++)
      #pragma unroll
      for (int m = 0; m < MR; m++) acc[g][m] = (f32x4){0.f,0.f,0.f,0.f};
    #pragma unroll
    for (int j = 0; j < 8; ++j){
      bf16x8 a[MR];
      #pragma unroll
      for (int m = 0; m < MR; m++)
        a[m] = *(const bf16x8*)(HB + offA[m] + kq * 256 + lg * 8 + j * 32);
      #pragma unroll
      for (int g = 0; g < 5; g++){
        bf16x8 bb = *(const bf16x8*)(bbase + (size_t)g * GATE_STRIDE + j * 32);
        #pragma unroll
        for (int m = 0; m < MR; m++)
          acc[g][m] = __builtin_amdgcn_mfma_f32_16x16x32_bf16(a[m], bb, acc[g][m], 0, 0, 0);
      }
    }
    #pragma unroll
    for (int m = 0; m < MR; m++){
      #pragma unroll
      for (int q = 0; q < 4; ++q){
        int r = lg * 4 + q;                      // C/D: row=(lane>>4)*4+q, col=lane&15
        #pragma unroll
        for (int g = 0; g < 5; g++) part[w][g][r][rc] = acc[g][m][q];
      }
      __syncthreads();
      int i = base + m * 16 + er;
      if (i < nr){
        float s[5];
        #pragma unroll
        for (int g = 0; g < 5; g++)
          s[g] = part[0][g][er][eu] + part[1][g][er][eu] + part[2][g][er][eu] + part[3][g][er][eu];
        float gv  = tanh_fast(s[0] + bg);
        float iv  = sigm(s[1] + bi);
        float f1v = sigm(s[2] + bf1);
        float f2v = sigm(s[3] + bf2);
        float ov  = sigm(s[4] + bo);
        int oL = sL[i], oR = sR[i], oD = dl[i];
        float cl = CF[oL + colu], cr = CF[oR + colu];
        float cv = gv * iv + f1v * cl + f2v * cr;
        float hv = ov * tanh_fast(cv);
        CF[oD + colu] = cv;
        HB[oD + colu] = f2bf(hv);
      }
      __syncthreads();
    }
  }
}

// ---------------- persistent tree kernel ----------------
// 512 blocks = 32 u-blocks x 16 m-groups, 256 threads (4 waves), 2 blocks/CU.
// u-block ub -> XCD ub%8: per-XCD weight slice 640KB stays L2-resident.
__global__ __launch_bounds__(256, 2) void tree_kernel(
    unsigned short* __restrict__ HB, float* __restrict__ CF,
    const unsigned short* __restrict__ WT, const float* __restrict__ b_red,
    const int* __restrict__ srcL, const int* __restrict__ srcR,
    const int* __restrict__ dstv, const int* __restrict__ cnt,
    const int* __restrict__ outsrc, float* __restrict__ out, int* bar){
  __shared__ float part[4][5][16][20];   // [wave][gate][row][col(+pad)]
  int bid = blockIdx.x;
  int ub = bid & 31, mg = bid >> 5;      // u-block 0..31, m-group 0..15
  int tid = threadIdx.x, w = tid >> 6, lane = tid & 63;
  int rc = lane & 15, lg = lane >> 4;
  int u0 = ub * 16;
  int eu = tid & 15, er = tid >> 4;      // epilogue coords
  int colu = u0 + eu;
  float bg  = b_red[colu];
  float bi  = b_red[Hn + colu];
  float bf1 = b_red[2 * Hn + colu];
  float bf2 = b_red[3 * Hn + colu];
  float bo  = b_red[4 * Hn + colu];
  int khalf = w >> 1, kq = w & 1;        // wave -> K quarter
  const unsigned short* bbase = WT + (size_t)(u0 + rc) * 1024 + khalf * 512 + kq * 256 + lg * 8;
  int maxlvl = cnt[0];

  int epoch = 1;
  for (int lvl = 1; lvl <= maxlvl; ++lvl, ++epoch){
    int nr = cnt[lvl];
    const int* sL = srcL + lvl * CAPL;
    const int* sR = srcR + lvl * CAPL;
    const int* dl = dstv + lvl * CAPL;
    if (nr >= 2048)
      do_tiles_level<4>(nr, mg, sL, sR, dl, HB, CF, bbase, part, w, rc, lg, khalf, kq, er, eu, colu, bg, bi, bf1, bf2, bo);
    else if (nr >= 512)
      do_tiles_level<2>(nr, mg, sL, sR, dl, HB, CF, bbase, part, w, rc, lg, khalf, kq, er, eu, colu, bg, bi, bf1, bf2, bo);
    else
      do_tiles_level<1>(nr, mg, sL, sR, dl, HB, CF, bbase, part, w, rc, lg, khalf, kq, er, eu, colu, bg, bi, bf1, bf2, bo);
    grid_barrier(bar, bid, epoch);
  }

  // final gather: out[b][u] = f32(h_root[b][u])
  if (bid < Bn){
    int src = outsrc[bid];
    out[bid * Hn + tid]       = bf2f(HB[src + tid]);
    out[bid * Hn + tid + 256] = bf2f(HB[src + tid + 256]);
  }
}

// ---------------- launch ----------------
extern "C" void kernel_launch(void* const* d_in, const int* in_sizes, int n_in,
                              void* d_out, int out_size, void* d_ws, size_t ws_size,
                              hipStream_t stream){
  (void)in_sizes; (void)n_in; (void)out_size; (void)ws_size;
  const float* sentence = (const float*)d_in[0];
  const int*   trans    = (const int*)d_in[1];
  const float* W_word   = (const float*)d_in[2];
  const float* b_word   = (const float*)d_in[3];
  const float* W_left   = (const float*)d_in[4];
  const float* W_right  = (const float*)d_in[5];
  const float* b_red    = (const float*)d_in[6];

  char* ws = (char*)d_ws;
  size_t off = 0;
  auto alloc = [&](size_t bytes) -> void* {
    void* p = ws + off;
    off += (bytes + 255) & ~((size_t)255);
    return p;
  };
  unsigned short* HB  = (unsigned short*)alloc((size_t)TOT_ROWS * Hn * 2); // bf16 h
  float*          CF  = (float*)alloc((size_t)TOT_ROWS * Hn * 4);          // f32 c
  unsigned short* WT  = (unsigned short*)alloc((size_t)2560 * 1024 * 2);   // [W_left;W_right]^T bf16
  unsigned short* SB  = (unsigned short*)alloc((size_t)LEAF_ROWS * En * 2);// sentence bf16
  unsigned short* WwT = (unsigned short*)alloc((size_t)1024 * En * 2);     // W_word^T bf16
  int* srcL   = (int*)alloc((size_t)NLVL * CAPL * 4);
  int* srcR   = (int*)alloc((size_t)NLVL * CAPL * 4);
  int* dstv   = (int*)alloc((size_t)NLVL * CAPL * 4);
  int* cnt    = (int*)alloc((size_t)NLVL * 4);
  int* outsrc = (int*)alloc((size_t)Bn * 4);
  int* bar    = (int*)alloc((size_t)(NBLK * FPAD + 1) * 4);
  float* outp = (float*)d_out;

  cvt_vec4<<<(LEAF_ROWS * En / 4) / 256, 256, 0, stream>>>((const float4*)sentence, (ushort4*)SB, LEAF_ROWS * En / 4);
  transpose_cvt<<<dim3(1024 / 32, En / 32), dim3(32, 8), 0, stream>>>(W_word, WwT, 1024, En, 0);
  transpose_cvt<<<dim3(2560 / 32, Hn / 32), dim3(32, 8), 0, stream>>>(W_left, WT, 2560, 1024, 0);
  transpose_cvt<<<dim3(2560 / 32, Hn / 32), dim3(32, 8), 0, stream>>>(W_right, WT, 2560, 1024, 512);
  precompute_ctrl<<<1, 128, 0, stream>>>(trans, srcL, srcR, dstv, cnt, outsrc, bar);
  word_gemm<<<dim3(8, LEAF_ROWS / 64), 256, 0, stream>>>(SB, WwT, b_word, HB, CF);
  tree_kernel<<<NBLK, 256, 0, stream>>>(HB, CF, WT, b_red, srcL, srcR, dstv, cnt, outsrc, outp, bar);
}

// Round 7
// 732.608 us; speedup vs baseline: 6.1057x; 5.9296x over previous
//
#include <hip/hip_runtime.h>
#include <hip/hip_bf16.h>

// SPINN: word GEMM + XCD-sharded persistent TreeLSTM (fence-free level sync).
// Trees sharded by batch&7 onto physical XCDs => all inter-level data flow is
// intra-XCD (shared L2 = coherence point, no wbl2/inv needed).
// B=128, L=64, E=512, H=512, T=127.

#define Bn 128
#define Ln 64
#define En 512
#define Hn 512
#define Tn 127
#define LEAF_ROWS (Bn*Ln)        // 8192 word rows
#define NODE_ROWS (Bn*(Ln-1))    // 8064 reduce-node rows
#define TOT_ROWS (LEAF_ROWS+NODE_ROWS)
#define NLVL 64
#define NXCD 8
#define CAPX 512                 // max rows per XCD-bin per level (16 trees * 32)
#define GATE_STRIDE (512*1024)   // WT element stride between gates
#define NBLK 512                 // persistent grid (2 blocks/CU => exactly fills chip)
#define FPAD 16                  // flag padding (one per 64B line)
#define MAXRANK 96
#define SPIN_CAP (1<<22)

// barrier/census state layout (ints), zeroed by precompute_ctrl each call
#define OFF_CENSUS 0                              // NXCD*FPAD
#define OFF_SFLAG  (OFF_CENSUS + NXCD*FPAD)       // NBLK*FPAD
#define OFF_SGEN   (OFF_SFLAG + NBLK*FPAD)        // FPAD
#define OFF_FX     (OFF_SGEN + FPAD)              // NXCD*MAXRANK*FPAD
#define OFF_GX     (OFF_FX + NXCD*MAXRANK*FPAD)   // NXCD*FPAD
#define BAR_INTS   (OFF_GX + NXCD*FPAD)

typedef __attribute__((ext_vector_type(8))) short bf16x8;
typedef __attribute__((ext_vector_type(4))) float f32x4;

static __device__ __forceinline__ float bf2f(unsigned short u){
  unsigned v = ((unsigned)u) << 16;
  float f; __builtin_memcpy(&f, &v, 4); return f;
}
static __device__ __forceinline__ unsigned short f2bf(float f){
  unsigned u; __builtin_memcpy(&u, &f, 4);
  u = u + 0x7FFFu + ((u >> 16) & 1u);   // round-nearest-even
  return (unsigned short)(u >> 16);
}
static __device__ __forceinline__ float sigm(float x){
  return 1.0f / (1.0f + __expf(-x));
}
static __device__ __forceinline__ float tanh_fast(float x){
  x = fminf(fmaxf(x, -15.0f), 15.0f);
  float t = __expf(2.0f * x);
  return (t - 1.0f) / (t + 1.0f);
}
static __device__ __forceinline__ int xcc_id(){
  unsigned v;
  asm volatile("s_getreg_b32 %0, hwreg(HW_REG_XCC_ID)" : "=s"(v));
  return (int)(v & 7);
}

// Per-XCD fence-free barrier among the nx blocks resident on XCD x.
// Data coherence: producers' stores reach the shared XCD L2 via the vmcnt(0)
// drain in __syncthreads; consumers first-touch-load via the same L2. Flags use
// relaxed agent-scope atomics (L3-coherent) purely for arrival signaling.
static __device__ __forceinline__ void xcd_barrier(int* bar, int x, int rank, int nx, int epoch){
  __syncthreads();
  int* fx = bar + OFF_FX + x * MAXRANK * FPAD;
  int* gx = bar + OFF_GX + x * FPAD;
  if (rank == 0){
    for (int i = threadIdx.x + 1; i < nx; i += 256){
      int c = 0;
      while (__hip_atomic_load(&fx[i * FPAD], __ATOMIC_RELAXED, __HIP_MEMORY_SCOPE_AGENT) < epoch && c < SPIN_CAP){
        __builtin_amdgcn_s_sleep(1); ++c;
      }
    }
    __syncthreads();
    if (threadIdx.x == 0)
      __hip_atomic_store(gx, epoch, __ATOMIC_RELAXED, __HIP_MEMORY_SCOPE_AGENT);
  } else {
    if (threadIdx.x == 0){
      __hip_atomic_store(&fx[rank * FPAD], epoch, __ATOMIC_RELAXED, __HIP_MEMORY_SCOPE_AGENT);
      int c = 0;
      while (__hip_atomic_load(gx, __ATOMIC_RELAXED, __HIP_MEMORY_SCOPE_AGENT) < epoch && c < SPIN_CAP){
        __builtin_amdgcn_s_sleep(2); ++c;
      }
    }
    __syncthreads();
  }
  asm volatile("" ::: "memory");
}

// ---------------- convert / transpose helpers ----------------

__global__ void cvt_vec4(const float4* __restrict__ x, ushort4* __restrict__ y, int n4){
  int i = blockIdx.x * 256 + threadIdx.x;
  if (i < n4){
    float4 v = x[i];
    ushort4 o;
    o.x = f2bf(v.x); o.y = f2bf(v.y); o.z = f2bf(v.z); o.w = f2bf(v.w);
    y[i] = o;
  }
}

// dstT[c*DS + koff + r] = bf16(src[r*CS + c]); tiles 32x32, block (32,8)
__global__ void transpose_cvt(const float* __restrict__ src, unsigned short* __restrict__ dstT,
                              int CS, int DS, int koff){
  __shared__ float tile[32][33];
  int c0 = blockIdx.x * 32, r0 = blockIdx.y * 32;
  int tx = threadIdx.x, ty = threadIdx.y;
  for (int i = ty; i < 32; i += 8) tile[i][tx] = src[(size_t)(r0 + i) * CS + c0 + tx];
  __syncthreads();
  for (int i = ty; i < 32; i += 8)
    dstT[(size_t)(c0 + i) * DS + koff + r0 + tx] = f2bf(tile[tx][i]);
}

// ---------------- control precompute: stack sim -> per-(XCD,level) dataflow ----------------
// One block, 128 threads. Bins nodes by (x = batch&7, level); zeroes all
// barrier/census state each call (deterministic across graph replays).
__global__ void precompute_ctrl(const int* __restrict__ trans,
                                int* __restrict__ srcL, int* __restrict__ srcR,
                                int* __restrict__ dstv, int* __restrict__ cnt,
                                int* __restrict__ outsrc, int* __restrict__ bar){
  __shared__ int stk[Bn][Ln + 1];    // padded
  __shared__ int scnt[NXCD * NLVL];
  __shared__ int smaxl[NXCD];
  int b = threadIdx.x;
  for (int i = b; i < NXCD * NLVL; i += 128) scnt[i] = 0;
  if (b < NXCD) smaxl[b] = 0;
  for (int i = b; i < BAR_INTS; i += 128) bar[i] = 0;
  __syncthreads();
  int x = b & 7;
  int sp = 0, bp = 0, nodecnt = 0;
  int act_next = trans[b * Tn];
  for (int t = 0; t < Tn; t++){
    int act = act_next;
    if (t + 1 < Tn) act_next = trans[b * Tn + t + 1];
    int ops = Tn - t;
    if (sp > ops) act = 2;                       // forced REDUCE (matches ref)
    if (act == 2){                               // REDUCE
      int R = stk[b][sp - 1], L = stk[b][sp - 2];
      int lvl = max(R >> 20, L >> 20) + 1;       // 1..63
      int slot = atomicAdd(&scnt[x * NLVL + lvl], 1);
      int base = (x * NLVL + lvl) * CAPX + slot;
      srcL[base] = (L & 0xFFFFF) * Hn;
      srcR[base] = (R & 0xFFFFF) * Hn;
      int noderow = LEAF_ROWS + b * (Ln - 1) + nodecnt;
      dstv[base] = noderow * Hn;
      stk[b][sp - 2] = noderow | (lvl << 20);
      sp -= 1; nodecnt++;
    } else {                                     // SHIFT (leaf: level 0)
      stk[b][sp] = b * Ln + min(bp, Ln - 1);
      sp += 1; bp += 1;
    }
  }
  int root = stk[b][max(sp - 1, 0)];
  outsrc[b] = (root & 0xFFFFF) * Hn;
  atomicMax(&smaxl[x], root >> 20);
  __syncthreads();
  for (int i = b; i < NXCD * NLVL; i += 128) cnt[i] = scnt[i];
  if (b < NXCD) cnt[NXCD * NLVL + b] = smaxl[b];
}

// ---------------- word GEMM: out = sentence @ W_word + b_word ----------------
__global__ __launch_bounds__(256) void word_gemm(
    const unsigned short* __restrict__ SB, const unsigned short* __restrict__ WwT,
    const float* __restrict__ b_word,
    unsigned short* __restrict__ HB, float* __restrict__ CF){
  int nt = blockIdx.x;            // 8 N-tiles (XCD-affine)
  int mt = blockIdx.y;            // 128 M-tiles
  int tid = threadIdx.x, w = tid >> 6, lane = tid & 63;
  int wm = w >> 1, wn = w & 1;
  int rc = lane & 15, lg = lane >> 4;
  const unsigned short* ap0 = SB + (size_t)(mt * 64 + wm * 32 + rc) * En + lg * 8;
  const unsigned short* ap1 = ap0 + (size_t)16 * En;
  const unsigned short* bp0 = WwT + (size_t)(nt * 128 + wn * 64 + rc) * En + lg * 8;
  f32x4 acc[2][4];
  #pragma unroll
  for (int h = 0; h < 2; h++)
    #pragma unroll
    for (int nb = 0; nb < 4; nb++) acc[h][nb] = (f32x4){0.f,0.f,0.f,0.f};
  #pragma unroll 4
  for (int k0 = 0; k0 < En; k0 += 32){
    bf16x8 a0 = *(const bf16x8*)(ap0 + k0);
    bf16x8 a1 = *(const bf16x8*)(ap1 + k0);
    #pragma unroll
    for (int nb = 0; nb < 4; nb++){
      bf16x8 bb = *(const bf16x8*)(bp0 + (size_t)nb * 16 * En + k0);
      acc[0][nb] = __builtin_amdgcn_mfma_f32_16x16x32_bf16(a0, bb, acc[0][nb], 0, 0, 0);
      acc[1][nb] = __builtin_amdgcn_mfma_f32_16x16x32_bf16(a1, bb, acc[1][nb], 0, 0, 0);
    }
  }
  #pragma unroll
  for (int nb = 0; nb < 4; nb++){
    int col = nt * 128 + wn * 64 + nb * 16 + rc;
    float bw = b_word[col];
    #pragma unroll
    for (int h = 0; h < 2; h++){
      #pragma unroll
      for (int q = 0; q < 4; q++){
        int row = mt * 64 + wm * 32 + h * 16 + lg * 4 + q;
        float v = acc[h][nb][q] + bw;
        if (col < Hn) HB[(size_t)row * Hn + col] = f2bf(v);
        else          CF[(size_t)row * Hn + (col - Hn)] = v;
      }
    }
  }
}

// ---------------- per-level tile processor (templated M-repeat) ----------------
// Tasks = rowtiles x 32 u-blocks, ub-major (temporally clustered weight slices
// stay L2-resident). K=1024 split over 4 waves; partials combined in LDS;
// fused TreeLSTM epilogue + scatter.
template<int MR>
static __device__ __forceinline__ void tiles_x(
    int nr, int rank, int nx, const int* sL, const int* sR, const int* dl,
    unsigned short* __restrict__ HB, float* __restrict__ CF,
    const unsigned short* __restrict__ WT, const float* __restrict__ b_red,
    float (*part)[5][16][20],
    int w, int rc, int lg, int khalf, int kq, int er, int eu)
{
  const int MB = 16 * MR;
  int ntl = (nr + MB - 1) / MB;
  int ntasks = ntl * 32;
  for (int task = rank; task < ntasks; task += nx){
    int ub = task / ntl;
    int tile = task - ub * ntl;
    int u0 = ub * 16;
    const unsigned short* bbase = WT + (size_t)(u0 + rc) * 1024 + khalf * 512 + kq * 256 + lg * 8;
    int base = tile * MB;
    int offA[MR];
    #pragma unroll
    for (int m = 0; m < MR; m++){
      int i = min(base + m * 16 + rc, nr - 1);
      offA[m] = (khalf ? sR : sL)[i];
    }
    f32x4 acc[5][MR];
    #pragma unroll
    for (int g = 0; g < 5; g++)
      #pragma unroll
      for (int m = 0; m < MR; m++) acc[g][m] = (f32x4){0.f,0.f,0.f,0.f};
    #pragma unroll
    for (int j = 0; j < 8; ++j){
      bf16x8 a[MR];
      #pragma unroll
      for (int m = 0; m < MR; m++)
        a[m] = *(const bf16x8*)(HB + offA[m] + kq * 256 + lg * 8 + j * 32);
      #pragma unroll
      for (int g = 0; g < 5; g++){
        bf16x8 bb = *(const bf16x8*)(bbase + (size_t)g * GATE_STRIDE + j * 32);
        #pragma unroll
        for (int m = 0; m < MR; m++)
          acc[g][m] = __builtin_amdgcn_mfma_f32_16x16x32_bf16(a[m], bb, acc[g][m], 0, 0, 0);
      }
    }
    int colu = u0 + eu;
    float bg  = b_red[colu];
    float bi  = b_red[Hn + colu];
    float bf1 = b_red[2 * Hn + colu];
    float bf2 = b_red[3 * Hn + colu];
    float bo  = b_red[4 * Hn + colu];
    #pragma unroll
    for (int m = 0; m < MR; m++){
      #pragma unroll
      for (int q = 0; q < 4; ++q){
        int r = lg * 4 + q;                      // C/D: row=(lane>>4)*4+q, col=lane&15
        #pragma unroll
        for (int g = 0; g < 5; g++) part[w][g][r][rc] = acc[g][m][q];
      }
      __syncthreads();
      int i = base + m * 16 + er;
      if (i < nr){
        float s[5];
        #pragma unroll
        for (int g = 0; g < 5; g++)
          s[g] = part[0][g][er][eu] + part[1][g][er][eu] + part[2][g][er][eu] + part[3][g][er][eu];
        float gv  = tanh_fast(s[0] + bg);
        float iv  = sigm(s[1] + bi);
        float f1v = sigm(s[2] + bf1);
        float f2v = sigm(s[3] + bf2);
        float ov  = sigm(s[4] + bo);
        int oL = sL[i], oR = sR[i], oD = dl[i];
        float cl = CF[oL + colu], cr = CF[oR + colu];
        float cv = gv * iv + f1v * cl + f2v * cr;
        float hv = ov * tanh_fast(cv);
        CF[oD + colu] = cv;
        HB[oD + colu] = f2bf(hv);
      }
      __syncthreads();
    }
  }
}

// ---------------- persistent XCD-sharded tree kernel ----------------
// 512 blocks (2/CU, chip-exact). Census: each block gets (xcd, rank). XCD x
// processes trees {b : b&7==x} level by level with fence-free local barriers.
__global__ __launch_bounds__(256, 2) void tree_kernel(
    unsigned short* __restrict__ HB, float* __restrict__ CF,
    const unsigned short* __restrict__ WT, const float* __restrict__ b_red,
    const int* __restrict__ srcL, const int* __restrict__ srcR,
    const int* __restrict__ dstv, const int* __restrict__ cnt,
    const int* __restrict__ outsrc, float* __restrict__ out, int* bar){
  __shared__ float part[4][5][16][20];   // [wave][gate][row][col(+pad)]
  __shared__ int s_tmp[2];
  int bid = blockIdx.x;
  int tid = threadIdx.x, w = tid >> 6, lane = tid & 63;
  int rc = lane & 15, lg = lane >> 4;
  int er = tid >> 4, eu = tid & 15;
  int khalf = w >> 1, kq = w & 1;

  int x = xcc_id();
  if (tid == 0)
    s_tmp[0] = __hip_atomic_fetch_add(&bar[OFF_CENSUS + x * FPAD], 1,
                                      __ATOMIC_RELAXED, __HIP_MEMORY_SCOPE_AGENT);
  __syncthreads();
  int rank = min(s_tmp[0], MAXRANK - 1);

  // one global start barrier so census counts are final
  {
    int* sfl  = bar + OFF_SFLAG;
    int* sgen = bar + OFF_SGEN;
    if (bid == 0){
      for (int i = tid; i < NBLK; i += 256){
        if (i){
          int c = 0;
          while (__hip_atomic_load(&sfl[i * FPAD], __ATOMIC_RELAXED, __HIP_MEMORY_SCOPE_AGENT) == 0 && c < SPIN_CAP){
            __builtin_amdgcn_s_sleep(1); ++c;
          }
        }
      }
      __syncthreads();
      if (tid == 0) __hip_atomic_store(sgen, 1, __ATOMIC_RELAXED, __HIP_MEMORY_SCOPE_AGENT);
    } else {
      if (tid == 0){
        __hip_atomic_store(&sfl[bid * FPAD], 1, __ATOMIC_RELAXED, __HIP_MEMORY_SCOPE_AGENT);
        int c = 0;
        while (__hip_atomic_load(sgen, __ATOMIC_RELAXED, __HIP_MEMORY_SCOPE_AGENT) == 0 && c < SPIN_CAP){
          __builtin_amdgcn_s_sleep(2); ++c;
        }
      }
      __syncthreads();
    }
  }

  if (tid == 0)
    s_tmp[1] = __hip_atomic_load(&bar[OFF_CENSUS + x * FPAD], __ATOMIC_RELAXED, __HIP_MEMORY_SCOPE_AGENT);
  __syncthreads();
  int nx = max(s_tmp[1], 1);

  int maxlvl = cnt[NXCD * NLVL + x];
  int epoch = 1;
  for (int lvl = 1; lvl <= maxlvl; ++lvl, ++epoch){
    int nr = cnt[x * NLVL + lvl];
    const int* sL = srcL + (x * NLVL + lvl) * CAPX;
    const int* sR = srcR + (x * NLVL + lvl) * CAPX;
    const int* dl = dstv + (x * NLVL + lvl) * CAPX;
    if (nr > 0){
      if (nr >= 256)
        tiles_x<4>(nr, rank, nx, sL, sR, dl, HB, CF, WT, b_red, part, w, rc, lg, khalf, kq, er, eu);
      else if (nr >= 96)
        tiles_x<2>(nr, rank, nx, sL, sR, dl, HB, CF, WT, b_red, part, w, rc, lg, khalf, kq, er, eu);
      else
        tiles_x<1>(nr, rank, nx, sL, sR, dl, HB, CF, WT, b_red, part, w, rc, lg, khalf, kq, er, eu);
    }
    xcd_barrier(bar, x, rank, nx, epoch);
  }

  // final gather for this XCD's 16 trees: out[b][u] = f32(h_root[b][u])
  for (int j = rank; j < 16; j += nx){
    int b = x + 8 * j;
    int src = outsrc[b];
    out[b * Hn + tid]       = bf2f(HB[src + tid]);
    out[b * Hn + tid + 256] = bf2f(HB[src + tid + 256]);
  }
}

// ---------------- launch ----------------
extern "C" void kernel_launch(void* const* d_in, const int* in_sizes, int n_in,
                              void* d_out, int out_size, void* d_ws, size_t ws_size,
                              hipStream_t stream){
  (void)in_sizes; (void)n_in; (void)out_size; (void)ws_size;
  const float* sentence = (const float*)d_in[0];
  const int*   trans    = (const int*)d_in[1];
  const float* W_word   = (const float*)d_in[2];
  const float* b_word   = (const float*)d_in[3];
  const float* W_left   = (const float*)d_in[4];
  const float* W_right  = (const float*)d_in[5];
  const float* b_red    = (const float*)d_in[6];

  char* ws = (char*)d_ws;
  size_t off = 0;
  auto alloc = [&](size_t bytes) -> void* {
    void* p = ws + off;
    off += (bytes + 255) & ~((size_t)255);
    return p;
  };
  unsigned short* HB  = (unsigned short*)alloc((size_t)TOT_ROWS * Hn * 2); // bf16 h
  float*          CF  = (float*)alloc((size_t)TOT_ROWS * Hn * 4);          // f32 c
  unsigned short* WT  = (unsigned short*)alloc((size_t)2560 * 1024 * 2);   // [W_left;W_right]^T bf16
  unsigned short* SB  = (unsigned short*)alloc((size_t)LEAF_ROWS * En * 2);// sentence bf16
  unsigned short* WwT = (unsigned short*)alloc((size_t)1024 * En * 2);     // W_word^T bf16
  int* srcL   = (int*)alloc((size_t)NXCD * NLVL * CAPX * 4);
  int* srcR   = (int*)alloc((size_t)NXCD * NLVL * CAPX * 4);
  int* dstv   = (int*)alloc((size_t)NXCD * NLVL * CAPX * 4);
  int* cnt    = (int*)alloc((size_t)(NXCD * NLVL + NXCD) * 4);
  int* outsrc = (int*)alloc((size_t)Bn * 4);
  int* bar    = (int*)alloc((size_t)BAR_INTS * 4);
  float* outp = (float*)d_out;

  cvt_vec4<<<(LEAF_ROWS * En / 4) / 256, 256, 0, stream>>>((const float4*)sentence, (ushort4*)SB, LEAF_ROWS * En / 4);
  transpose_cvt<<<dim3(1024 / 32, En / 32), dim3(32, 8), 0, stream>>>(W_word, WwT, 1024, En, 0);
  transpose_cvt<<<dim3(2560 / 32, Hn / 32), dim3(32, 8), 0, stream>>>(W_left, WT, 2560, 1024, 0);
  transpose_cvt<<<dim3(2560 / 32, Hn / 32), dim3(32, 8), 0, stream>>>(W_right, WT, 2560, 1024, 512);
  precompute_ctrl<<<1, 128, 0, stream>>>(trans, srcL, srcR, dstv, cnt, outsrc, bar);
  word_gemm<<<dim3(8, LEAF_ROWS / 64), 256, 0, stream>>>(SB, WwT, b_word, HB, CF);
  tree_kernel<<<NBLK, 256, 0, stream>>>(HB, CF, WT, b_red, srcL, srcR, dstv, cnt, outsrc, outp, bar);
}